// Round 2
// baseline (62.545 us; speedup 1.0000x reference)
//
#include <hip/hip_runtime.h>
#include <float.h>

#define C_    512
#define H_    38
#define W_    50
#define HW_   (H_ * W_)       // 1900
#define NROIS 1024
#define PS    7
#define PRE   14              // PS*2
#define NCELL 49              // PS*PS
#define CQ    128             // channels per block (quarter)

typedef float vfloat4 __attribute__((ext_vector_type(4)));

// ---------------------------------------------------------------------------
// Transpose bottom (C, H*W) -> (H*W, C) so corner gathers are coalesced
// across channels. 32x32 LDS tile transpose.
// ---------------------------------------------------------------------------
__global__ __launch_bounds__(256) void transpose_kernel(
    const float* __restrict__ in, float* __restrict__ out) {
    __shared__ float tile[32][33];
    const int pix0 = blockIdx.x * 32;   // H*W tile base
    const int c0   = blockIdx.y * 32;   // channel tile base
    const int tx = threadIdx.x & 31;
    const int ty = threadIdx.x >> 5;    // 0..7

    for (int i = ty; i < 32; i += 8) {
        int c = c0 + i, pix = pix0 + tx;
        tile[i][tx] = (pix < HW_) ? in[c * HW_ + pix] : 0.0f;
    }
    __syncthreads();
    for (int i = ty; i < 32; i += 8) {
        int pix = pix0 + i, c = c0 + tx;
        if (pix < HW_) out[pix * C_ + c] = tile[tx][i];
    }
}

// ---------------------------------------------------------------------------
// Main crop-and-maxpool kernel.
// grid = NROIS * 4 blocks; block = 256 threads (4 waves).
// Block (n, cq) handles ROI n, channels [cq*128, cq*128+128).
// pix_stride/c_stride parameterize src layout:
//   transposed path: src[(y*W + x)*512 + c]   -> pix_stride=512, c_stride=1
//   fallback path:   src[c*1900 + (y*W + x)]  -> pix_stride=1,   c_stride=1900
// ---------------------------------------------------------------------------
__global__ __launch_bounds__(256) void croppool_kernel(
    const float* __restrict__ src, const float* __restrict__ rois,
    float* __restrict__ out, int pix_stride, int c_stride) {

    const int n  = blockIdx.x >> 2;
    const int cq = blockIdx.x & 3;
    const int cbase = cq * CQ;
    const int tid = threadIdx.x;

    __shared__ float outtile[CQ * NCELL];          // [c_local][cell], stride 49 (odd -> bank-conflict-free)
    __shared__ int   xi0[PRE], xi1[PRE], yi0[PRE], yi1[PRE];
    __shared__ float xw0[PRE], xw1[PRE], yw0[PRE], yw1[PRE];

    // --- per-ROI interpolation tables (align_corners=True + zeros padding) ---
    if (tid < 2 * PRE) {
        const int  j   = tid % PRE;
        const bool isy = tid >= PRE;
        const float r1 = rois[n * 5 + (isy ? 2 : 1)] * (1.0f / 16.0f);
        const float r2 = rois[n * 5 + (isy ? 4 : 3)] * (1.0f / 16.0f);
        const float sz = isy ? (float)(H_ - 1) : (float)(W_ - 1);
        const int  szi = isy ? (H_ - 1) : (W_ - 1);
        const float t0 = (r2 - r1) / sz;                 // t00 / t11
        const float tc = (r1 + r2 - sz) / sz;            // t02 / t12
        const float base = -1.0f + (float)j * (2.0f / 13.0f);   // linspace(-1,1,14)
        const float g     = t0 * base + tc;              // normalized coord
        const float coord = (g + 1.0f) * 0.5f * sz;      // input pixel coord
        const float f = floorf(coord);
        const float a = coord - f;
        const int i0 = (int)f;
        const int i1 = i0 + 1;
        const float w0 = (i0 >= 0 && i0 <= szi) ? (1.0f - a) : 0.0f;
        const float w1 = (i1 >= 0 && i1 <= szi) ? a : 0.0f;
        const int i0c = min(max(i0, 0), szi);
        const int i1c = min(max(i1, 0), szi);
        if (isy) { yi0[j] = i0c; yi1[j] = i1c; yw0[j] = w0; yw1[j] = w1; }
        else     { xi0[j] = i0c; xi1[j] = i1c; xw0[j] = w0; xw1[j] = w1; }
    }
    __syncthreads();

    const int wave = tid >> 6;
    const int lane = tid & 63;
    const int s64  = 64 * c_stride;
    const float* srcc = src + (size_t)(cbase + lane) * c_stride;

    // --- compute: each wave owns cells {wave, wave+4, ...}; lane covers 2 ch ---
    for (int cell = wave; cell < NCELL; cell += 4) {
        const int py = cell / PS, px = cell % PS;
        float m0 = -FLT_MAX, m1 = -FLT_MAX;
        #pragma unroll
        for (int ry = 0; ry < 2; ++ry) {
            const int gy = 2 * py + ry;
            const int y0 = yi0[gy], y1 = yi1[gy];
            const float wy0 = yw0[gy], wy1 = yw1[gy];
            #pragma unroll
            for (int rx = 0; rx < 2; ++rx) {
                const int gx = 2 * px + rx;
                const int x0 = xi0[gx], x1 = xi1[gx];
                const float wx0 = xw0[gx], wx1 = xw1[gx];
                const float* p00 = srcc + (size_t)(y0 * W_ + x0) * pix_stride;
                const float* p01 = srcc + (size_t)(y0 * W_ + x1) * pix_stride;
                const float* p10 = srcc + (size_t)(y1 * W_ + x0) * pix_stride;
                const float* p11 = srcc + (size_t)(y1 * W_ + x1) * pix_stride;
                const float v0 = wy0 * (wx0 * p00[0]   + wx1 * p01[0])
                               + wy1 * (wx0 * p10[0]   + wx1 * p11[0]);
                const float v1 = wy0 * (wx0 * p00[s64] + wx1 * p01[s64])
                               + wy1 * (wx0 * p10[s64] + wx1 * p11[s64]);
                m0 = fmaxf(m0, v0);
                m1 = fmaxf(m1, v1);
            }
        }
        outtile[lane * NCELL + cell]        = m0;   // bank-conflict-free (stride 49)
        outtile[(lane + 64) * NCELL + cell] = m1;
    }
    __syncthreads();

    // --- flush: LDS tile IS the output sub-block layout -> contiguous float4 ---
    const vfloat4* lsrc = (const vfloat4*)outtile;
    vfloat4* dst = (vfloat4*)out + (size_t)n * (C_ * NCELL / 4) + cq * (CQ * NCELL / 4);
    for (int i = tid; i < CQ * NCELL / 4; i += 256) {
        __builtin_nontemporal_store(lsrc[i], &dst[i]);
    }
}

extern "C" void kernel_launch(void* const* d_in, const int* in_sizes, int n_in,
                              void* d_out, int out_size, void* d_ws, size_t ws_size,
                              hipStream_t stream) {
    const float* bottom = (const float*)d_in[0];   // (1, 512, 38, 50)
    const float* rois   = (const float*)d_in[1];   // (1024, 5)
    float* out = (float*)d_out;                    // (1024, 512, 7, 7)

    const size_t trans_bytes = (size_t)HW_ * C_ * sizeof(float);
    if (ws_size >= trans_bytes) {
        float* trans = (float*)d_ws;
        dim3 tgrid((HW_ + 31) / 32, C_ / 32);
        transpose_kernel<<<tgrid, 256, 0, stream>>>(bottom, trans);
        croppool_kernel<<<NROIS * 4, 256, 0, stream>>>(trans, rois, out, C_, 1);
    } else {
        // fallback: read original (C, H*W) layout directly (uncoalesced but correct)
        croppool_kernel<<<NROIS * 4, 256, 0, stream>>>(bottom, rois, out, 1, HW_);
    }
}